// Round 9
// baseline (256.524 us; speedup 1.0000x reference)
//
#include <hip/hip_runtime.h>
#include <stdint.h>

#define N_TOK  16384
#define EMB    512
#define NEMB   2048
#define NCHUNK 64            // 32 templates per chunk
#define CWIN   2.5e-4f       // ref-f32-grid + bf16 score-noise margin (passed R5-R8)
#define WCAP   524288

typedef __attribute__((ext_vector_type(8))) short s16x8;
typedef __attribute__((ext_vector_type(4))) float f32x4;

__device__ __forceinline__ unsigned short f2bf(float f) {   // RNE f32 -> bf16
  unsigned u = __float_as_uint(f);
  u += 0x7fffu + ((u >> 16) & 1u);
  return (unsigned short)(u >> 16);
}
// monotone f32 -> u32 (total order, NaN sorts above all reals)
__device__ __forceinline__ unsigned mapf(float f) {
  unsigned u = __float_as_uint(f);
  return (u >> 31) ? ~u : (u | 0x80000000u);
}
__device__ __forceinline__ float unmapf(unsigned u) {
  return __uint_as_float((u >> 31) ? (u & 0x7fffffffu) : ~u);
}

// numpy pairwise_sum emulation for sum(x*x) over 512 contiguous f32.
__device__ __forceinline__ float pairwise512_sq(const float* se, int lane) {
  int l = lane & 31;
  int b = l >> 3, j = l & 7;
  const float* base = se + b * 128 + j;
  float x = base[0];
  float r = __fmul_rn(x, x);
#pragma unroll
  for (int k = 1; k < 16; ++k) {
    float y = base[8 * k];
    r = __fadd_rn(r, __fmul_rn(y, y));
  }
  r = __fadd_rn(r, __shfl_xor(r, 1));
  r = __fadd_rn(r, __shfl_xor(r, 2));
  r = __fadd_rn(r, __shfl_xor(r, 4));
  r = __fadd_rn(r, __shfl_xor(r, 8));
  r = __fadd_rn(r, __shfl_xor(r, 16));
  return r;
}

// ---------- kernel 1: fused prep, 4 rows per block (wave per row) ----------
__global__ __launch_bounds__(256) void prep_kernel(
    const float* __restrict__ tmp, const float* __restrict__ enc,
    unsigned short* __restrict__ thi, float* __restrict__ tsq,
    unsigned short* __restrict__ ehi, float* __restrict__ esq,
    int* __restrict__ wcount) {
  __shared__ float se[4][EMB];
  int wv = threadIdx.x >> 6, lane = threadIdx.x & 63;
  int row = blockIdx.x * 4 + wv;                             // 18432 rows
  if (blockIdx.x == 0 && threadIdx.x == 0) *wcount = 0;
  bool isT = row < NEMB;
  const float* src = isT ? (tmp + (size_t)row * EMB)
                         : (enc + (size_t)(row - NEMB) * EMB);
  const float4* p = (const float4*)src + lane * 2;
  float4 v0 = p[0], v1 = p[1];
  float f[8] = {v0.x, v0.y, v0.z, v0.w, v1.x, v1.y, v1.z, v1.w};
  unsigned h[8];
#pragma unroll
  for (int i = 0; i < 8; ++i) { h[i] = f2bf(f[i]); se[wv][lane * 8 + i] = f[i]; }
  uint4 packed = { h[0] | (h[1] << 16), h[2] | (h[3] << 16),
                   h[4] | (h[5] << 16), h[6] | (h[7] << 16) };
  unsigned short* dsth = isT ? (thi + (size_t)row * EMB)
                             : (ehi + (size_t)(row - NEMB) * EMB);
  ((uint4*)dsth)[lane] = packed;
  __syncthreads();
  float s = pairwise512_sq(se[wv], lane);
  if (lane == 0) { if (isT) tsq[row] = s; else esq[row - NEMB] = s; }
}

// ---------- kernel 2: GEMM, A direct-to-regs, B double-buffered (1 barrier/kb) ----------
// grid 2048: tokb = bid>>4 (128 tokens), mb = bid&15 (128 templates). BK=64.
__global__ __launch_bounds__(256, 3) void score_kernel(
    const unsigned short* __restrict__ ehi, const unsigned short* __restrict__ thi,
    const float* __restrict__ tsq, unsigned long long* __restrict__ keyc) {
  __shared__ __align__(16) char smem[33792];     // B dbuf 2x16KB; epilogue 33792B
  uint4* sBuf0 = (uint4*)smem;
  uint4* sBuf1 = (uint4*)(smem + 16384);
  const int tid = threadIdx.x, w = tid >> 6, lane = tid & 63;
  const int q = lane >> 4, r = lane & 15;
  const int tokb = (int)blockIdx.x >> 4;
  const int mb   = (int)blockIdx.x & 15;

  const unsigned short* aRow[4];
#pragma unroll
  for (int ti = 0; ti < 4; ++ti)
    aRow[ti] = ehi + (size_t)(tokb * 128 + ((w >> 1) * 4 + ti) * 16 + r) * EMB + q * 8;

  f32x4 acc[4][4];
#pragma unroll
  for (int ti = 0; ti < 4; ++ti)
#pragma unroll
    for (int j = 0; j < 4; ++j) acc[ti][j] = (f32x4){0.f, 0.f, 0.f, 0.f};

  // stage B for kb into buf
#define STAGE_B(kb, buf)                                                          \
  {                                                                               \
    _Pragma("unroll")                                                             \
    for (int n = 0; n < 4; ++n) {                                                 \
      int p = w + n * 4, tile = p >> 1, ks = p & 1;                               \
      const unsigned short* gb = thi +                                            \
          (size_t)(mb * 128 + tile * 16 + r) * EMB + (kb) * 64 + ks * 32 + q * 8; \
      __builtin_amdgcn_global_load_lds(                                           \
          (const __attribute__((address_space(1))) void*)gb,                      \
          (__attribute__((address_space(3))) void*)((buf) + (tile * 2 + ks) * 64),\
          16, 0, 0);                                                              \
    }                                                                             \
  }

  STAGE_B(0, sBuf0);
  __syncthreads();                               // drain B(0)
  for (int kb = 0; kb < 8; ++kb) {
    // A for this kb: direct global->reg, issued BEFORE next-B so the A-wait
    // (vmcnt) before MFMA does not drain the B prefetch.
    s16x8 a[8];
#pragma unroll
    for (int ti = 0; ti < 4; ++ti) {
      a[ti * 2 + 0] = *(const s16x8*)(aRow[ti] + kb * 64);
      a[ti * 2 + 1] = *(const s16x8*)(aRow[ti] + kb * 64 + 32);
    }
    if (kb < 7) { if (kb & 1) STAGE_B(kb + 1, sBuf0) else STAGE_B(kb + 1, sBuf1) }
    const s16x8* cur = (const s16x8*)((kb & 1) ? sBuf1 : sBuf0);
#pragma unroll
    for (int ks = 0; ks < 2; ++ks) {
      s16x8 bfr[4];
#pragma unroll
      for (int j = 0; j < 4; ++j)
        bfr[j] = cur[((((w & 1) * 4 + j) * 2 + ks) << 6) + lane];
#pragma unroll
      for (int ti = 0; ti < 4; ++ti)
#pragma unroll
        for (int j = 0; j < 4; ++j)
          acc[ti][j] = __builtin_amdgcn_mfma_f32_16x16x32_bf16(a[ti * 2 + ks], bfr[j],
                                                               acc[ti][j], 0, 0, 0);
    }
    __syncthreads();                             // drains B(kb+1); 1 barrier per kb
  }

  // ---- epilogue: per-(token,32-row-chunk) best key with tight bit ----
  unsigned* S = (unsigned*)smem;                 // 256 cells x 33 u32 (pad)
  float tq[4];
#pragma unroll
  for (int j = 0; j < 4; ++j) tq[j] = tsq[mb * 128 + ((w & 1) * 4 + j) * 16 + r];
#pragma unroll
  for (int phase = 0; phase < 2; ++phase) {
    if ((w & 1) == phase) {
#pragma unroll
      for (int ti = 0; ti < 4; ++ti)
#pragma unroll
        for (int i = 0; i < 4; ++i) {
          int tl = (w >> 1) * 64 + ti * 16 + q * 4 + i;
#pragma unroll
          for (int j = 0; j < 4; ++j) {
            float s = tq[j] - 2.0f * acc[ti][j][i];
            S[(tl * 2 + (j >> 1)) * 33 + (j & 1) * 16 + r] = mapf(s);
          }
        }
    }
    __syncthreads();
    {
      int cell = tid, tl = cell >> 1, cl = cell & 1;
      unsigned m1 = 0xffffffffu, m2 = 0xffffffffu; int sl1 = 0;
#pragma unroll
      for (int sidx = 0; sidx < 32; ++sidx) {    // sidx ascending = m ascending
        unsigned u = S[cell * 33 + sidx];
        if (u < m1) { m2 = m1; m1 = u; sl1 = sidx; }
        else m2 = u < m2 ? u : m2;
      }
      bool tight = !(unmapf(m2) - unmapf(m1) >= CWIN);   // NaN-safe -> tight
      int mwin = mb * 128 + (phase * 2 + cl) * 32 + sl1;
      unsigned long long key = ((unsigned long long)m1 << 32)
                             | ((unsigned)tight << 31) | (unsigned)mwin;
      int chunk = mb * 4 + phase * 2 + cl;
      keyc[(size_t)chunk * N_TOK + tokb * 128 + tl] = key;
    }
    __syncthreads();
  }
}

// ---------- kernel 3: 64-chunk key merge, flag, worklist; inits rkey ----------
__global__ __launch_bounds__(256) void merge_kernel(
    const unsigned long long* __restrict__ keyc, int* __restrict__ bestIdx,
    int* __restrict__ flag, int* __restrict__ work, int* __restrict__ wcount,
    unsigned long long* __restrict__ rkey) {
  int t = blockIdx.x * 256 + threadIdx.x;
  if (t >= N_TOK) return;
  rkey[t] = ~0ULL;
  unsigned long long K = ~0ULL;
  for (int c = 0; c < NCHUNK; ++c) {
    unsigned long long k = keyc[(size_t)c * N_TOK + t];
    K = k < K ? k : K;
  }
  float bestf = unmapf((unsigned)(K >> 32));
  bool tight = ((K >> 31) & 1ULL) != 0;
  int idx = (int)(K & 0x7fffffffULL);
  bestIdx[t] = idx;
  bool nanC = !(bestf == bestf);
  float limit = bestf + CWIN;
  unsigned long long cmask = 0;
  for (int c = 0; c < NCHUNK; ++c) {
    float cf = unmapf((unsigned)(keyc[(size_t)c * N_TOK + t] >> 32));
    if (nanC || !(cf > limit)) cmask |= (1ULL << c);       // NaN-safe candidate
  }
  int ncand = __popcll(cmask);
  bool ok = !nanC && !tight && (ncand <= 1) && idx >= 0 && idx < NEMB;
  flag[t] = ok ? 0 : 1;
  if (!ok) {
    unsigned long long m = cmask;
    while (m) {
      int c = __ffsll((long long)m) - 1;
      m &= m - 1;
      int pos = atomicAdd(wcount, 1);
      if (pos < WCAP) work[pos] = t * NCHUNK + c;
    }
  }
}

// ---------- kernel 4: wave-per-pair f32-emulated rescan (32-row chunks) ----------
__global__ __launch_bounds__(256) void refine_kernel(
    const float* __restrict__ enc, const float* __restrict__ tmp,
    const float* __restrict__ esq, const float* __restrict__ tsq,
    const int* __restrict__ work, const int* __restrict__ wcount,
    unsigned long long* __restrict__ rkey) {
  int total = *wcount; if (total > WCAP) total = WCAP;
  int lane = threadIdx.x & 63;
  int gw = (blockIdx.x * 256 + threadIdx.x) >> 6;
  int nw = (gridDim.x * 256) >> 6;
  for (int p = gw; p < total; p += nw) {
    int item = work[p];
    int token = item >> 6, c = item & 63;
    const float4* er = (const float4*)(enc + (size_t)token * EMB);
    float4 e0 = er[lane * 2], e1 = er[lane * 2 + 1];
    float e2s = esq[token];
    unsigned long long lkey = ~0ULL;
    for (int jj = 0; jj < 32; ++jj) {
      int m = c * 32 + jj;
      const float4* tr = (const float4*)(tmp + (size_t)m * EMB);
      float4 t0 = tr[lane * 2], t1 = tr[lane * 2 + 1];
      double s = (double)t0.x * e0.x + (double)t0.y * e0.y
               + (double)t0.z * e0.z + (double)t0.w * e0.w
               + (double)t1.x * e1.x + (double)t1.y * e1.y
               + (double)t1.z * e1.z + (double)t1.w * e1.w;
#pragma unroll
      for (int mask = 1; mask < 64; mask <<= 1) s += __shfl_xor(s, mask);
      if (lane == 0) {
        float M  = (float)s;
        float d1 = __fadd_rn(e2s, -__fmul_rn(2.0f, M));
        float d2 = __fadd_rn(d1, tsq[m]);          // dist ~512 > 0: bits monotone
        unsigned long long key =
            ((unsigned long long)__float_as_uint(d2) << 32) | (unsigned)m;
        lkey = key < lkey ? key : lkey;
      }
    }
    if (lane == 0 && lkey != ~0ULL) atomicMin(&rkey[token], lkey);
  }
}

// ---------- kernel 5: gather f32 rows + zidx as f32 ----------
__global__ void gather_kernel(const float* __restrict__ tmp, const int* __restrict__ bestIdx,
                              const int* __restrict__ flag,
                              const unsigned long long* __restrict__ rkey,
                              float* __restrict__ out) {
  int token = blockIdx.x * 4 + (threadIdx.x >> 6);
  int lane = threadIdx.x & 63;
  int idx = flag[token] ? (int)(unsigned)(rkey[token] & 0xffffffffULL) : bestIdx[token];
  idx = idx < 0 ? 0 : (idx > NEMB - 1 ? NEMB - 1 : idx);
  const float4* src = (const float4*)(tmp + (size_t)idx * EMB) + lane * 2;
  float4* dst = (float4*)(out + (size_t)token * EMB) + lane * 2;
  dst[0] = src[0];
  dst[1] = src[1];
  if (lane == 0) out[(size_t)N_TOK * EMB + token] = (float)idx;
}

extern "C" void kernel_launch(void* const* d_in, const int* in_sizes, int n_in,
                              void* d_out, int out_size, void* d_ws, size_t ws_size,
                              hipStream_t stream) {
  const float* enc = (const float*)d_in[0];
  const float* tmp = (const float*)d_in[1];
  float* out = (float*)d_out;
  char* ws = (char*)d_ws;
  unsigned short* thi = (unsigned short*)ws;                 //  2,097,152 B
  unsigned short* ehi = (unsigned short*)(ws + 2097152);     // 16,777,216 B
  float* tsq      = (float*)(ws + 18874368);                 //      8,192 B
  float* esq      = (float*)(ws + 18882560);                 //     65,536 B
  unsigned long long* keyc = (unsigned long long*)(ws + 18948096); // 8,388,608 B
  int*   bestIdx  = (int*)  (ws + 27336704);                 //     65,536 B
  int*   flag     = (int*)  (ws + 27402240);                 //     65,536 B
  unsigned long long* rkey = (unsigned long long*)(ws + 27467776); // 131,072 B
  int*   wcount   = (int*)  (ws + 27598848);                 //         64 B
  int*   work     = (int*)  (ws + 27598912);                 //  2,097,152 B

  prep_kernel  <<<4608,      256, 0, stream>>>(tmp, enc, thi, tsq, ehi, esq, wcount);
  score_kernel <<<2048,      256, 0, stream>>>(ehi, thi, tsq, keyc);
  merge_kernel <<<N_TOK/256, 256, 0, stream>>>(keyc, bestIdx, flag, work, wcount, rkey);
  refine_kernel<<<512,       256, 0, stream>>>(enc, tmp, esq, tsq, work, wcount, rkey);
  gather_kernel<<<N_TOK/4,   256, 0, stream>>>(tmp, bestIdx, flag, rkey, out);
}